// Round 4
// baseline (100.959 us; speedup 1.0000x reference)
//
#include <hip/hip_runtime.h>
#include <hip/hip_cooperative_groups.h>
#include <math.h>

namespace cg = cooperative_groups;

#define BLOCK 256
#define CHUNK 256
#define MAXGRID 1024
#define RBLOCKS 1024

// ===========================================================================
// Fused cooperative kernel (variable grid size, chosen by host occupancy query)
//  Phase A: grid-wide sum of q^2 -> partials[gridDim.x]  (double, deterministic)
//  grid.sync()
//  Phase B: every block reduces partials identically -> inv_norm
//  Phase C: chunked pointwise cov/inv_cov/sigmoid, LDS-staged coalesced stores
// ===========================================================================
__global__ __launch_bounds__(BLOCK, 4) void gp_fused(
    const float4* __restrict__ q,
    const float* __restrict__ scales,
    const float* __restrict__ opac_in,
    double* __restrict__ partials,
    float* __restrict__ cov,
    float* __restrict__ inv_cov,
    float* __restrict__ opac_out,
    int n) {
    __shared__ float s_mat[2 * CHUNK * 9];
    __shared__ float s_sc[CHUNK * 3];
    __shared__ double s_red[BLOCK / 64];

    const int tid = threadIdx.x;
    const int nblk = gridDim.x;

    // ---------------- Phase A ----------------
    double acc = 0.0;
    for (int i = blockIdx.x * BLOCK + tid; i < n; i += nblk * BLOCK) {
        float4 v = q[i];
        acc += (double)v.x * v.x + (double)v.y * v.y +
               (double)v.z * v.z + (double)v.w * v.w;
    }
#pragma unroll
    for (int off = 32; off > 0; off >>= 1) acc += __shfl_down(acc, off);
    if ((tid & 63) == 0) s_red[tid >> 6] = acc;
    __syncthreads();
    if (tid == 0)
        partials[blockIdx.x] = s_red[0] + s_red[1] + s_red[2] + s_red[3];

    cg::this_grid().sync();

    // ---------------- Phase B ----------------
    double a2 = 0.0;
    for (int i = tid; i < nblk; i += BLOCK) a2 += partials[i];
#pragma unroll
    for (int off = 32; off > 0; off >>= 1) a2 += __shfl_down(a2, off);
    __syncthreads();
    if ((tid & 63) == 0) s_red[tid >> 6] = a2;
    __syncthreads();
    const float inv_norm =
        (float)(1.0 / sqrt(s_red[0] + s_red[1] + s_red[2] + s_red[3]));

    // ---------------- Phase C ----------------
    const int nchunks = (n + CHUNK - 1) / CHUNK;
    for (int c = blockIdx.x; c < nchunks; c += nblk) {
        const int c0 = c * CHUNK;
        const int count = min(CHUNK, n - c0);

        __syncthreads();

        const int nsf = count * 3;
        const int nsf4 = nsf >> 2;
        const float4* sc4 = (const float4*)(scales + (size_t)c0 * 3);
        if (tid < nsf4) {
            float4 sv = sc4[tid];
            s_sc[4 * tid + 0] = sv.x;
            s_sc[4 * tid + 1] = sv.y;
            s_sc[4 * tid + 2] = sv.z;
            s_sc[4 * tid + 3] = sv.w;
        }
        {
            int r = nsf - (nsf4 << 2);
            if (tid < r) s_sc[(nsf4 << 2) + tid] =
                scales[(size_t)c0 * 3 + (nsf4 << 2) + tid];
        }

        float4 qi = make_float4(0.f, 0.f, 0.f, 0.f);
        float op = 0.f;
        if (tid < count) {
            qi = q[c0 + tid];
            op = opac_in[c0 + tid];
        }
        __syncthreads();

        if (tid < count) {
            float w = qi.x * inv_norm;
            float x = qi.y * inv_norm;
            float y = qi.z * inv_norm;
            float z = qi.w * inv_norm;

            float xx = x * x, yy = y * y, zz = z * z;
            float xy = x * y, xz = x * z, yz = y * z;
            float xw = x * w, yw = y * w, zw = z * w;

            float r00 = 1.f - 2.f * (yy + zz);
            float r01 = 2.f * (xy - zw);
            float r02 = 2.f * (xz + yw);
            float r10 = 2.f * (xy + zw);
            float r11 = 1.f - 2.f * (xx + zz);
            float r12 = 2.f * (yz - xw);
            float r20 = 2.f * (xz - yw);
            float r21 = 2.f * (yz + xw);
            float r22 = 1.f - 2.f * (xx + yy);

            float s0 = s_sc[3 * tid + 0];
            float s1 = s_sc[3 * tid + 1];
            float s2 = s_sc[3 * tid + 2];

            float e0 = expf(2.f * s0), e1 = expf(2.f * s1), e2 = expf(2.f * s2);
            float f0 = 1.f / e0, f1 = 1.f / e1, f2 = 1.f / e2;

            float* mc = &s_mat[tid * 9];
            float* mi = &s_mat[CHUNK * 9 + tid * 9];
            {
                float a0 = r00 * e0, a1 = r01 * e1, a2 = r02 * e2;
                float b0 = r10 * e0, b1 = r11 * e1, b2 = r12 * e2;
                float g0 = r20 * e0, g1 = r21 * e1, g2 = r22 * e2;
                float m00 = a0 * r00 + a1 * r01 + a2 * r02;
                float m01 = a0 * r10 + a1 * r11 + a2 * r12;
                float m02 = a0 * r20 + a1 * r21 + a2 * r22;
                float m11 = b0 * r10 + b1 * r11 + b2 * r12;
                float m12 = b0 * r20 + b1 * r21 + b2 * r22;
                float m22 = g0 * r20 + g1 * r21 + g2 * r22;
                mc[0] = m00; mc[1] = m01; mc[2] = m02;
                mc[3] = m01; mc[4] = m11; mc[5] = m12;
                mc[6] = m02; mc[7] = m12; mc[8] = m22;
            }
            {
                float a0 = r00 * f0, a1 = r01 * f1, a2 = r02 * f2;
                float b0 = r10 * f0, b1 = r11 * f1, b2 = r12 * f2;
                float g0 = r20 * f0, g1 = r21 * f1, g2 = r22 * f2;
                float m00 = a0 * r00 + a1 * r01 + a2 * r02;
                float m01 = a0 * r10 + a1 * r11 + a2 * r12;
                float m02 = a0 * r20 + a1 * r21 + a2 * r22;
                float m11 = b0 * r10 + b1 * r11 + b2 * r12;
                float m12 = b0 * r20 + b1 * r21 + b2 * r22;
                float m22 = g0 * r20 + g1 * r21 + g2 * r22;
                mi[0] = m00; mi[1] = m01; mi[2] = m02;
                mi[3] = m01; mi[4] = m11; mi[5] = m12;
                mi[6] = m02; mi[7] = m12; mi[8] = m22;
            }
            opac_out[c0 + tid] = 1.f / (1.f + expf(-op));
        }
        __syncthreads();

        const int nf = count * 9;
        const int nfv = nf >> 2;
        float4* covo = (float4*)(cov + (size_t)c0 * 9);
        float4* invo = (float4*)(inv_cov + (size_t)c0 * 9);
        const float4* mc4 = (const float4*)s_mat;
        const float4* mi4 = (const float4*)(s_mat + CHUNK * 9);
        for (int j = tid; j < nfv; j += BLOCK) {
            covo[j] = mc4[j];
            invo[j] = mi4[j];
        }
        for (int j = (nfv << 2) + tid; j < nf; j += BLOCK) {
            cov[(size_t)c0 * 9 + j] = s_mat[j];
            inv_cov[(size_t)c0 * 9 + j] = s_mat[CHUNK * 9 + j];
        }
    }
}

// ===========================================================================
// Fallback path (proven R2 structure): reduce kernel + per-chunk main kernel
// ===========================================================================
__global__ __launch_bounds__(BLOCK) void gp_reduce_sq(
    const float4* __restrict__ q4, int n4, double* __restrict__ partials) {
    __shared__ double sdata[BLOCK];
    double acc = 0.0;
    int stride = gridDim.x * blockDim.x;
    for (int i = blockIdx.x * blockDim.x + threadIdx.x; i < n4; i += stride) {
        float4 v = q4[i];
        acc += (double)v.x * v.x + (double)v.y * v.y +
               (double)v.z * v.z + (double)v.w * v.w;
    }
    sdata[threadIdx.x] = acc;
    __syncthreads();
    for (int s = BLOCK / 2; s > 0; s >>= 1) {
        if (threadIdx.x < s) sdata[threadIdx.x] += sdata[threadIdx.x + s];
        __syncthreads();
    }
    if (threadIdx.x == 0) partials[blockIdx.x] = sdata[0];
}

__global__ __launch_bounds__(BLOCK) void gp_main(
    const float4* __restrict__ q,
    const float* __restrict__ scales,
    const float* __restrict__ opac_in,
    const double* __restrict__ partials,
    float* __restrict__ cov,
    float* __restrict__ inv_cov,
    float* __restrict__ opac_out,
    int n) {
    __shared__ union SU {
        double red[4];
        float mat[2 * CHUNK * 9];
    } u;
    __shared__ float s_sc[CHUNK * 3];

    const int tid = threadIdx.x;
    const int c0 = blockIdx.x * CHUNK;
    const int count = min(CHUNK, n - c0);

    float4 qi = make_float4(0.f, 0.f, 0.f, 0.f);
    float op = 0.f;
    if (tid < count) {
        qi = q[c0 + tid];
        op = opac_in[c0 + tid];
    }
    const int nsf = count * 3;
    const int nsf4 = nsf >> 2;
    const float4* sc4 = (const float4*)(scales + (size_t)c0 * 3);
    float4 sv = make_float4(0.f, 0.f, 0.f, 0.f);
    if (tid < nsf4) sv = sc4[tid];

    double acc = 0.0;
#pragma unroll
    for (int k = 0; k < RBLOCKS / 256; ++k) acc += partials[tid + 256 * k];
#pragma unroll
    for (int off = 32; off > 0; off >>= 1) acc += __shfl_down(acc, off);
    if ((tid & 63) == 0) u.red[tid >> 6] = acc;

    if (tid < nsf4) {
        s_sc[4 * tid + 0] = sv.x;
        s_sc[4 * tid + 1] = sv.y;
        s_sc[4 * tid + 2] = sv.z;
        s_sc[4 * tid + 3] = sv.w;
    }
    {
        int r = nsf - (nsf4 << 2);
        if (tid < r) s_sc[(nsf4 << 2) + tid] =
            scales[(size_t)c0 * 3 + (nsf4 << 2) + tid];
    }
    __syncthreads();
    double tot = u.red[0] + u.red[1] + u.red[2] + u.red[3];
    const float inv_norm = (float)(1.0 / sqrt(tot));
    __syncthreads();

    if (tid < count) {
        float w = qi.x * inv_norm;
        float x = qi.y * inv_norm;
        float y = qi.z * inv_norm;
        float z = qi.w * inv_norm;
        float xx = x * x, yy = y * y, zz = z * z;
        float xy = x * y, xz = x * z, yz = y * z;
        float xw = x * w, yw = y * w, zw = z * w;
        float r00 = 1.f - 2.f * (yy + zz);
        float r01 = 2.f * (xy - zw);
        float r02 = 2.f * (xz + yw);
        float r10 = 2.f * (xy + zw);
        float r11 = 1.f - 2.f * (xx + zz);
        float r12 = 2.f * (yz - xw);
        float r20 = 2.f * (xz - yw);
        float r21 = 2.f * (yz + xw);
        float r22 = 1.f - 2.f * (xx + yy);
        float s0 = s_sc[3 * tid + 0];
        float s1 = s_sc[3 * tid + 1];
        float s2 = s_sc[3 * tid + 2];
        float e0 = expf(2.f * s0), e1 = expf(2.f * s1), e2 = expf(2.f * s2);
        float f0 = 1.f / e0, f1 = 1.f / e1, f2 = 1.f / e2;
        float* mc = &u.mat[tid * 9];
        float* mi = &u.mat[CHUNK * 9 + tid * 9];
        {
            float a0 = r00 * e0, a1 = r01 * e1, a2 = r02 * e2;
            float b0 = r10 * e0, b1 = r11 * e1, b2 = r12 * e2;
            float g0 = r20 * e0, g1 = r21 * e1, g2 = r22 * e2;
            float m00 = a0 * r00 + a1 * r01 + a2 * r02;
            float m01 = a0 * r10 + a1 * r11 + a2 * r12;
            float m02 = a0 * r20 + a1 * r21 + a2 * r22;
            float m11 = b0 * r10 + b1 * r11 + b2 * r12;
            float m12 = b0 * r20 + b1 * r21 + b2 * r22;
            float m22 = g0 * r20 + g1 * r21 + g2 * r22;
            mc[0] = m00; mc[1] = m01; mc[2] = m02;
            mc[3] = m01; mc[4] = m11; mc[5] = m12;
            mc[6] = m02; mc[7] = m12; mc[8] = m22;
        }
        {
            float a0 = r00 * f0, a1 = r01 * f1, a2 = r02 * f2;
            float b0 = r10 * f0, b1 = r11 * f1, b2 = r12 * f2;
            float g0 = r20 * f0, g1 = r21 * f1, g2 = r22 * f2;
            float m00 = a0 * r00 + a1 * r01 + a2 * r02;
            float m01 = a0 * r10 + a1 * r11 + a2 * r12;
            float m02 = a0 * r20 + a1 * r21 + a2 * r22;
            float m11 = b0 * r10 + b1 * r11 + b2 * r12;
            float m12 = b0 * r20 + b1 * r21 + b2 * r22;
            float m22 = g0 * r20 + g1 * r21 + g2 * r22;
            mi[0] = m00; mi[1] = m01; mi[2] = m02;
            mi[3] = m01; mi[4] = m11; mi[5] = m12;
            mi[6] = m02; mi[7] = m12; mi[8] = m22;
        }
        opac_out[c0 + tid] = 1.f / (1.f + expf(-op));
    }
    __syncthreads();

    const int nf = count * 9;
    const int nfv = nf >> 2;
    float4* covo = (float4*)(cov + (size_t)c0 * 9);
    float4* invo = (float4*)(inv_cov + (size_t)c0 * 9);
    const float4* mc4 = (const float4*)u.mat;
    const float4* mi4 = (const float4*)(u.mat + CHUNK * 9);
    for (int j = tid; j < nfv; j += BLOCK) {
        covo[j] = mc4[j];
        invo[j] = mi4[j];
    }
    for (int j = (nfv << 2) + tid; j < nf; j += BLOCK) {
        cov[(size_t)c0 * 9 + j] = u.mat[j];
        inv_cov[(size_t)c0 * 9 + j] = u.mat[CHUNK * 9 + j];
    }
}

extern "C" void kernel_launch(void* const* d_in, const int* in_sizes, int n_in,
                              void* d_out, int out_size, void* d_ws, size_t ws_size,
                              hipStream_t stream) {
    const float4* q = (const float4*)d_in[0];      // (N,4)
    const float* scales = (const float*)d_in[1];   // (N,3)
    const float* opac = (const float*)d_in[2];     // (N,1)
    int n = in_sizes[0] / 4;

    float* out = (float*)d_out;
    float* cov = out;
    float* inv_cov = out + (size_t)n * 9;
    float* opac_out = out + (size_t)n * 18;

    double* partials = (double*)d_ws;  // up to MAXGRID doubles

    // Size the cooperative grid from queried occupancy (deterministic per
    // device -> identical path on every call; host-side queries only).
    int occ = 0;
    hipError_t qe = hipOccupancyMaxActiveBlocksPerMultiprocessor(
        &occ, gp_fused, BLOCK, 0);
    int num_cu = 0;
    hipError_t ae = hipDeviceGetAttribute(
        &num_cu, hipDeviceAttributeMultiprocessorCount, 0);

    bool coop_ok = false;
    if (qe == hipSuccess && ae == hipSuccess && occ > 0 && num_cu > 0) {
        int grid = occ * num_cu;
        if (grid > MAXGRID) grid = MAXGRID;
        if (grid >= 64) {
            void* args[] = {(void*)&q, (void*)&scales, (void*)&opac,
                            (void*)&partials, (void*)&cov, (void*)&inv_cov,
                            (void*)&opac_out, (void*)&n};
            hipError_t le = hipLaunchCooperativeKernel(
                (void*)gp_fused, dim3(grid), dim3(BLOCK), args, 0, stream);
            coop_ok = (le == hipSuccess);
        }
    }

    if (!coop_ok) {
        // Proven two-kernel fallback
        gp_reduce_sq<<<RBLOCKS, BLOCK, 0, stream>>>(q, n, partials);
        int nblocks = (n + CHUNK - 1) / CHUNK;
        gp_main<<<nblocks, BLOCK, 0, stream>>>(
            q, scales, opac, partials, cov, inv_cov, opac_out, n);
    }
}

// Round 5
// 46.898 us; speedup vs baseline: 2.1527x; 2.1527x over previous
//
#include <hip/hip_runtime.h>
#include <math.h>

#define BLOCK 256
#define CHUNK 256
#define RBLOCKS 1024

typedef float f32x4 __attribute__((ext_vector_type(4)));

// ---------------------------------------------------------------------------
// Pass 1: grid-stride sum of q^2 -> partials[RBLOCKS] (double, deterministic)
//         + fused sigmoid(opacity) stream (overlaps under the q read)
// ---------------------------------------------------------------------------
__global__ __launch_bounds__(BLOCK, 4) void gp_pass1(
    const float4* __restrict__ q4,
    const float* __restrict__ opac_in,
    int n,
    double* __restrict__ partials,
    float* __restrict__ opac_out) {
    __shared__ double s_red[BLOCK / 64];
    const int tid = threadIdx.x;
    const int stride = gridDim.x * BLOCK;

    double acc = 0.0;
    for (int i = blockIdx.x * BLOCK + tid; i < n; i += stride) {
        float4 v = q4[i];
        acc += (double)v.x * v.x + (double)v.y * v.y +
               (double)v.z * v.z + (double)v.w * v.w;
    }

    // fused opacity: sigmoid, streaming loads/stores
    for (int i = blockIdx.x * BLOCK + tid; i < n; i += stride) {
        float o = __builtin_nontemporal_load(opac_in + i);
        float r = 1.f / (1.f + __expf(-o));
        __builtin_nontemporal_store(r, opac_out + i);
    }

#pragma unroll
    for (int off = 32; off > 0; off >>= 1) acc += __shfl_down(acc, off);
    if ((tid & 63) == 0) s_red[tid >> 6] = acc;
    __syncthreads();
    if (tid == 0)
        partials[blockIdx.x] = s_red[0] + s_red[1] + s_red[2] + s_red[3];
}

// ---------------------------------------------------------------------------
// Pass 2: per-chunk pointwise cov/inv_cov. Every block redundantly reduces
// the RBLOCKS partials (deterministic identical result), then LDS-stages the
// two 3x3 outputs and streams them with coalesced non-temporal float4 stores.
// ---------------------------------------------------------------------------
__global__ __launch_bounds__(BLOCK, 8) void gp_main(
    const float4* __restrict__ q,
    const float* __restrict__ scales,
    const double* __restrict__ partials,
    float* __restrict__ cov,
    float* __restrict__ inv_cov,
    int n) {
    __shared__ union SU {
        double red[BLOCK / 64];
        float mat[2 * CHUNK * 9];  // [0..2304) cov, [2304..4608) inv_cov
    } u;

    const int tid = threadIdx.x;
    const int c0 = blockIdx.x * CHUNK;
    const int count = min(CHUNK, n - c0);

    // issue input loads early
    float4 qi = make_float4(0.f, 0.f, 0.f, 0.f);
    float s0 = 0.f, s1 = 0.f, s2 = 0.f;
    if (tid < count) {
        qi = q[c0 + tid];  // L3-resident from pass 1
        const float* sc = scales + 3 * (size_t)(c0 + tid);
        s0 = sc[0];
        s1 = sc[1];
        s2 = sc[2];
    }

    // redundant deterministic norm reduction (partials are L2-resident)
    double acc = partials[tid] + partials[tid + 256] +
                 partials[tid + 512] + partials[tid + 768];
#pragma unroll
    for (int off = 32; off > 0; off >>= 1) acc += __shfl_down(acc, off);
    if ((tid & 63) == 0) u.red[tid >> 6] = acc;
    __syncthreads();
    const float inv_norm =
        (float)(1.0 / sqrt(u.red[0] + u.red[1] + u.red[2] + u.red[3]));
    __syncthreads();  // u.red reads done before u.mat overwrites

    if (tid < count) {
        float w = qi.x * inv_norm;
        float x = qi.y * inv_norm;
        float y = qi.z * inv_norm;
        float z = qi.w * inv_norm;

        float xx = x * x, yy = y * y, zz = z * z;
        float xy = x * y, xz = x * z, yz = y * z;
        float xw = x * w, yw = y * w, zw = z * w;

        float r00 = 1.f - 2.f * (yy + zz);
        float r01 = 2.f * (xy - zw);
        float r02 = 2.f * (xz + yw);
        float r10 = 2.f * (xy + zw);
        float r11 = 1.f - 2.f * (xx + zz);
        float r12 = 2.f * (yz - xw);
        float r20 = 2.f * (xz - yw);
        float r21 = 2.f * (yz + xw);
        float r22 = 1.f - 2.f * (xx + yy);

        float e0 = __expf(2.f * s0), e1 = __expf(2.f * s1), e2 = __expf(2.f * s2);
        float f0 = 1.f / e0, f1 = 1.f / e1, f2 = 1.f / e2;

        float* mc = &u.mat[tid * 9];
        float* mi = &u.mat[CHUNK * 9 + tid * 9];
        {
            float a0 = r00 * e0, a1 = r01 * e1, a2 = r02 * e2;
            float b0 = r10 * e0, b1 = r11 * e1, b2 = r12 * e2;
            float g0 = r20 * e0, g1 = r21 * e1, g2 = r22 * e2;
            float m00 = a0 * r00 + a1 * r01 + a2 * r02;
            float m01 = a0 * r10 + a1 * r11 + a2 * r12;
            float m02 = a0 * r20 + a1 * r21 + a2 * r22;
            float m11 = b0 * r10 + b1 * r11 + b2 * r12;
            float m12 = b0 * r20 + b1 * r21 + b2 * r22;
            float m22 = g0 * r20 + g1 * r21 + g2 * r22;
            mc[0] = m00; mc[1] = m01; mc[2] = m02;
            mc[3] = m01; mc[4] = m11; mc[5] = m12;
            mc[6] = m02; mc[7] = m12; mc[8] = m22;
        }
        {
            float a0 = r00 * f0, a1 = r01 * f1, a2 = r02 * f2;
            float b0 = r10 * f0, b1 = r11 * f1, b2 = r12 * f2;
            float g0 = r20 * f0, g1 = r21 * f1, g2 = r22 * f2;
            float m00 = a0 * r00 + a1 * r01 + a2 * r02;
            float m01 = a0 * r10 + a1 * r11 + a2 * r12;
            float m02 = a0 * r20 + a1 * r21 + a2 * r22;
            float m11 = b0 * r10 + b1 * r11 + b2 * r12;
            float m12 = b0 * r20 + b1 * r21 + b2 * r22;
            float m22 = g0 * r20 + g1 * r21 + g2 * r22;
            mi[0] = m00; mi[1] = m01; mi[2] = m02;
            mi[3] = m01; mi[4] = m11; mi[5] = m12;
            mi[6] = m02; mi[7] = m12; mi[8] = m22;
        }
    }
    __syncthreads();

    // coalesced non-temporal float4 stores
    const int nf = count * 9;
    const int nfv = nf >> 2;
    f32x4* covo = (f32x4*)(cov + (size_t)c0 * 9);
    f32x4* invo = (f32x4*)(inv_cov + (size_t)c0 * 9);
    const f32x4* mc4 = (const f32x4*)u.mat;
    const f32x4* mi4 = (const f32x4*)(u.mat + CHUNK * 9);
    for (int j = tid; j < nfv; j += BLOCK) {
        __builtin_nontemporal_store(mc4[j], covo + j);
        __builtin_nontemporal_store(mi4[j], invo + j);
    }
    for (int j = (nfv << 2) + tid; j < nf; j += BLOCK) {
        cov[(size_t)c0 * 9 + j] = u.mat[j];
        inv_cov[(size_t)c0 * 9 + j] = u.mat[CHUNK * 9 + j];
    }
}

extern "C" void kernel_launch(void* const* d_in, const int* in_sizes, int n_in,
                              void* d_out, int out_size, void* d_ws, size_t ws_size,
                              hipStream_t stream) {
    const float4* q = (const float4*)d_in[0];      // (N,4)
    const float* scales = (const float*)d_in[1];   // (N,3)
    const float* opac = (const float*)d_in[2];     // (N,1)
    int n = in_sizes[0] / 4;

    float* out = (float*)d_out;
    float* cov = out;                        // N*9
    float* inv_cov = out + (size_t)n * 9;    // N*9
    float* opac_out = out + (size_t)n * 18;  // N

    double* partials = (double*)d_ws;        // RBLOCKS doubles

    gp_pass1<<<RBLOCKS, BLOCK, 0, stream>>>(q, opac, n, partials, opac_out);

    int nblocks = (n + CHUNK - 1) / CHUNK;
    gp_main<<<nblocks, BLOCK, 0, stream>>>(
        q, scales, partials, cov, inv_cov, n);
}

// Round 6
// 43.503 us; speedup vs baseline: 2.3207x; 1.0780x over previous
//
#include <hip/hip_runtime.h>
#include <math.h>

#define RBLOCKS 1024
#define RTHREADS 256
#define CHUNK 256
#define BLOCK 256

typedef float f32x4 __attribute__((ext_vector_type(4)));

// ---------------------------------------------------------------------------
// Stage 1: per-block partial sums of q^2 (double accumulation, deterministic)
// ---------------------------------------------------------------------------
__global__ __launch_bounds__(RTHREADS) void gp_reduce_sq(
    const float4* __restrict__ q4, int n4, double* __restrict__ partials) {
    __shared__ double sdata[RTHREADS];
    double acc = 0.0;
    int stride = gridDim.x * blockDim.x;
    for (int i = blockIdx.x * blockDim.x + threadIdx.x; i < n4; i += stride) {
        float4 v = q4[i];
        acc += (double)v.x * v.x + (double)v.y * v.y +
               (double)v.z * v.z + (double)v.w * v.w;
    }
    sdata[threadIdx.x] = acc;
    __syncthreads();
    for (int s = RTHREADS / 2; s > 0; s >>= 1) {
        if (threadIdx.x < s) sdata[threadIdx.x] += sdata[threadIdx.x + s];
        __syncthreads();
    }
    if (threadIdx.x == 0) partials[blockIdx.x] = sdata[0];
}

// ---------------------------------------------------------------------------
// Stage 2: every block redundantly reduces the 1024 partials (deterministic,
// identical result), computes its chunk of 256 gaussians, stages the 3x3
// outputs in LDS, and streams them with coalesced NON-TEMPORAL float4 stores.
// ---------------------------------------------------------------------------
__global__ __launch_bounds__(BLOCK) void gp_main(
    const float4* __restrict__ q,
    const float* __restrict__ scales,
    const float* __restrict__ opac_in,
    const double* __restrict__ partials,
    float* __restrict__ cov,
    float* __restrict__ inv_cov,
    float* __restrict__ opac_out,
    int n) {
    __shared__ union SU {
        double red[4];
        float mat[2 * CHUNK * 9];  // [0..2304) cov, [2304..4608) inv_cov
    } u;
    __shared__ float s_sc[CHUNK * 3];

    const int tid = threadIdx.x;
    const int c0 = blockIdx.x * CHUNK;
    const int count = min(CHUNK, n - c0);

    // ---- issue input loads early ----
    float4 qi = make_float4(0.f, 0.f, 0.f, 0.f);
    float op = 0.f;
    if (tid < count) {
        qi = q[c0 + tid];
        op = opac_in[c0 + tid];
    }
    // stage scales via coalesced float4 loads
    const int nsf = count * 3;
    const int nsf4 = nsf >> 2;
    const float4* sc4 = (const float4*)(scales + (size_t)c0 * 3);
    float4 sv = make_float4(0.f, 0.f, 0.f, 0.f);
    if (tid < nsf4) sv = sc4[tid];

    // ---- norm: reduce 1024 partials (deterministic, same in every block) ----
    double acc = 0.0;
#pragma unroll
    for (int k = 0; k < RBLOCKS / 256; ++k) acc += partials[tid + 256 * k];
#pragma unroll
    for (int off = 32; off > 0; off >>= 1) acc += __shfl_down(acc, off);
    if ((tid & 63) == 0) u.red[tid >> 6] = acc;

    // park scales into LDS
    if (tid < nsf4) {
        s_sc[4 * tid + 0] = sv.x;
        s_sc[4 * tid + 1] = sv.y;
        s_sc[4 * tid + 2] = sv.z;
        s_sc[4 * tid + 3] = sv.w;
    }
    {
        int r = nsf - (nsf4 << 2);
        if (tid < r) s_sc[(nsf4 << 2) + tid] =
            scales[(size_t)c0 * 3 + (nsf4 << 2) + tid];
    }
    __syncthreads();

    double tot = u.red[0] + u.red[1] + u.red[2] + u.red[3];
    const float inv_norm = (float)(1.0 / sqrt(tot));
    __syncthreads();  // all reads of u.red done before u.mat overwrites it

    // ---- compute ----
    if (tid < count) {
        float w = qi.x * inv_norm;
        float x = qi.y * inv_norm;
        float y = qi.z * inv_norm;
        float z = qi.w * inv_norm;

        float xx = x * x, yy = y * y, zz = z * z;
        float xy = x * y, xz = x * z, yz = y * z;
        float xw = x * w, yw = y * w, zw = z * w;

        float r00 = 1.f - 2.f * (yy + zz);
        float r01 = 2.f * (xy - zw);
        float r02 = 2.f * (xz + yw);
        float r10 = 2.f * (xy + zw);
        float r11 = 1.f - 2.f * (xx + zz);
        float r12 = 2.f * (yz - xw);
        float r20 = 2.f * (xz - yw);
        float r21 = 2.f * (yz + xw);
        float r22 = 1.f - 2.f * (xx + yy);

        float s0 = s_sc[3 * tid + 0];
        float s1 = s_sc[3 * tid + 1];
        float s2 = s_sc[3 * tid + 2];

        float e0 = __expf(2.f * s0), e1 = __expf(2.f * s1), e2 = __expf(2.f * s2);
        float f0 = 1.f / e0, f1 = 1.f / e1, f2 = 1.f / e2;

        float* mc = &u.mat[tid * 9];
        float* mi = &u.mat[CHUNK * 9 + tid * 9];
        {
            float a0 = r00 * e0, a1 = r01 * e1, a2 = r02 * e2;
            float b0 = r10 * e0, b1 = r11 * e1, b2 = r12 * e2;
            float g0 = r20 * e0, g1 = r21 * e1, g2 = r22 * e2;
            float m00 = a0 * r00 + a1 * r01 + a2 * r02;
            float m01 = a0 * r10 + a1 * r11 + a2 * r12;
            float m02 = a0 * r20 + a1 * r21 + a2 * r22;
            float m11 = b0 * r10 + b1 * r11 + b2 * r12;
            float m12 = b0 * r20 + b1 * r21 + b2 * r22;
            float m22 = g0 * r20 + g1 * r21 + g2 * r22;
            mc[0] = m00; mc[1] = m01; mc[2] = m02;
            mc[3] = m01; mc[4] = m11; mc[5] = m12;
            mc[6] = m02; mc[7] = m12; mc[8] = m22;
        }
        {
            float a0 = r00 * f0, a1 = r01 * f1, a2 = r02 * f2;
            float b0 = r10 * f0, b1 = r11 * f1, b2 = r12 * f2;
            float g0 = r20 * f0, g1 = r21 * f1, g2 = r22 * f2;
            float m00 = a0 * r00 + a1 * r01 + a2 * r02;
            float m01 = a0 * r10 + a1 * r11 + a2 * r12;
            float m02 = a0 * r20 + a1 * r21 + a2 * r22;
            float m11 = b0 * r10 + b1 * r11 + b2 * r12;
            float m12 = b0 * r20 + b1 * r21 + b2 * r22;
            float m22 = g0 * r20 + g1 * r21 + g2 * r22;
            mi[0] = m00; mi[1] = m01; mi[2] = m02;
            mi[3] = m01; mi[4] = m11; mi[5] = m12;
            mi[6] = m02; mi[7] = m12; mi[8] = m22;
        }
        // opacity (coalesced scalar store)
        opac_out[c0 + tid] = 1.f / (1.f + __expf(-op));
    }
    __syncthreads();

    // ---- coalesced NON-TEMPORAL float4 stores of cov / inv_cov ----
    const int nf = count * 9;
    const int nfv = nf >> 2;
    f32x4* covo = (f32x4*)(cov + (size_t)c0 * 9);
    f32x4* invo = (f32x4*)(inv_cov + (size_t)c0 * 9);
    const f32x4* mc4 = (const f32x4*)u.mat;
    const f32x4* mi4 = (const f32x4*)(u.mat + CHUNK * 9);
    for (int j = tid; j < nfv; j += BLOCK) {
        __builtin_nontemporal_store(mc4[j], covo + j);
        __builtin_nontemporal_store(mi4[j], invo + j);
    }
    for (int j = (nfv << 2) + tid; j < nf; j += BLOCK) {
        cov[(size_t)c0 * 9 + j] = u.mat[j];
        inv_cov[(size_t)c0 * 9 + j] = u.mat[CHUNK * 9 + j];
    }
}

extern "C" void kernel_launch(void* const* d_in, const int* in_sizes, int n_in,
                              void* d_out, int out_size, void* d_ws, size_t ws_size,
                              hipStream_t stream) {
    const float4* q = (const float4*)d_in[0];      // (N,4)
    const float* scales = (const float*)d_in[1];   // (N,3)
    const float* opac = (const float*)d_in[2];     // (N,1)
    int n = in_sizes[0] / 4;

    float* out = (float*)d_out;
    float* cov = out;                        // N*9
    float* inv_cov = out + (size_t)n * 9;    // N*9
    float* opac_out = out + (size_t)n * 18;  // N

    double* partials = (double*)d_ws;        // RBLOCKS doubles

    gp_reduce_sq<<<RBLOCKS, RTHREADS, 0, stream>>>(q, n, partials);

    int nblocks = (n + CHUNK - 1) / CHUNK;
    gp_main<<<nblocks, BLOCK, 0, stream>>>(
        q, scales, opac, partials, cov, inv_cov, opac_out, n);
}